// Round 4
// baseline (236.284 us; speedup 1.0000x reference)
//
#include <hip/hip_runtime.h>

// ---------- types ----------
typedef _Float16 f16;
typedef _Float16 f16x4 __attribute__((ext_vector_type(4)));
typedef _Float16 f16x8 __attribute__((ext_vector_type(8)));
typedef float    f32x4 __attribute__((ext_vector_type(4)));

#define N_ROWS 100000
#define RT 1563           // 1563 * 64 = 100032 padded rows
#define LSX 264           // X tile f16 row stride: 256 data + 8 pad (132 dw ≡ 4 mod 32 → spreads banks)
#define LSH1 136
#define LSH2 72

// ws: weights only
#define W1T_OFF 0
#define W1T_BYTES (256 * 256 * 2)
#define W2T_OFF W1T_BYTES

// arena (bytes): full X tile staged ONCE (64*264*2 = 33792); h1s/h2s overlay after K-loop
#define ARENA 33792
#define H1S 0             // 64*136*2 = 17408
#define H2S 17408         // 64*72*2  =  9216  -> 26624 <= ARENA

// ---------- prep: combined, transposed f16 weights (coalesced writes) ----------
__global__ void prep_w(const float* __restrict__ wz1, const float* __restrict__ wh1,
                       const float* __restrict__ wz2, const float* __restrict__ wh2,
                       f16* __restrict__ W1T, f16* __restrict__ W2T) {
    const int b = blockIdx.x;
    if (b < 256) {
        int idx = b * 256 + threadIdx.x;
        int c = idx >> 8, k = idx & 255;           // consecutive tid -> consecutive k -> coalesced store
        const float* w = (c < 128) ? wz1 : wh1;
        int cc = c & 127;
        W1T[c * 256 + k] = (f16)(w[k * 128 + cc] + w[384 * 128 + k * 128 + cc]);
    } else {
        int idx = (b - 256) * 256 + threadIdx.x;
        int c = idx >> 7, k = idx & 127;
        const float* w = (c < 64) ? wz2 : wh2;
        int cc = c & 63;
        W2T[c * 128 + k] = (f16)(w[k * 64 + cc] + w[192 * 64 + k * 64 + cc]);
    }
}

// gate: relu( tanh(hp) * (1 - sigmoid(zp)) ) with a single v_rcp.
// tanh(h)*(1-sig(z)) = (e^{2h}-1) / ((e^{2h}+1)*(1+e^{z})).
// hp clamped (tanh(15)==1 in f32) so e2h=inf can't make inf*0=NaN; zp=+inf -> rcp(inf)=0 -> 0 (correct limit).
__device__ __forceinline__ float gate(float zp, float hp) {
    float e2h = __expf(2.0f * fminf(hp, 15.0f));
    float ez  = __expf(zp);
    float r   = __builtin_amdgcn_rcpf((e2h + 1.0f) * (1.0f + ez));
    return fmaxf((e2h - 1.0f) * r, 0.0f);
}

// ---------- fused: 64 rows/block; X staged to LDS once, barrier-free K-loop,
// ---------- W1/W2 fragments straight from L2 ----------
__global__ __launch_bounds__(256, 4) void fused(
    const float* __restrict__ x,
    const f16* __restrict__ W1T, const f16* __restrict__ W2T,
    const float* __restrict__ bz1, const float* __restrict__ bh1,
    const float* __restrict__ bz2, const float* __restrict__ bh2,
    const float* __restrict__ wl1, const float* __restrict__ bl1,
    const float* __restrict__ wl2, const float* __restrict__ bl2,
    float* __restrict__ out)
{
    __shared__ __align__(16) char arena[ARENA];
    const int tid = threadIdx.x, lane = tid & 63, wave = tid >> 6;
    const int ln = lane & 15, quad = lane >> 4;
    const int r0 = blockIdx.x * 64;

    // staging thread mapping (X only): thread -> (row, 8-float col group)
    const int xr = tid >> 2, xcg = tid & 3;
    int gxr = r0 + xr; if (gxr >= N_ROWS) gxr = N_ROWS - 1;
    const float* xp = x + (size_t)gxr * 256 + (xcg << 3);

    f16* Xs = (f16*)arena;

    // ---- stage the full 64x256 tile, ONE barrier total in the K phase ----
    {
        float4 xa[8], xb[8];
#pragma unroll
        for (int kc = 0; kc < 8; ++kc) {
            xa[kc] = *(const float4*)(xp + kc * 32);
            xb[kc] = *(const float4*)(xp + kc * 32 + 4);
        }
#pragma unroll
        for (int kc = 0; kc < 8; ++kc) {
            *(f16x8*)&Xs[xr * LSX + kc * 32 + (xcg << 3)] =
                (f16x8){(f16)xa[kc].x,(f16)xa[kc].y,(f16)xa[kc].z,(f16)xa[kc].w,
                        (f16)xb[kc].x,(f16)xb[kc].y,(f16)xb[kc].z,(f16)xb[kc].w};
        }
    }

    // P1 wave tiles: z m-tiles {2w,2w+1}, h {2w+8,2w+9}; n-tiles 0..3 (16 rows each)
    const int Mz = 2 * wave;
    const f16* wb[4];
#pragma unroll
    for (int mi = 0; mi < 4; ++mi) {
        const int M = (mi < 2) ? (Mz + mi) : (8 + Mz + mi - 2);
        wb[mi] = W1T + (size_t)(M * 16 + ln) * 256 + quad * 8;
    }

    __syncthreads();

    f32x4 acc[4][4];                                   // [mi][nt]
#pragma unroll
    for (int a = 0; a < 4; ++a)
#pragma unroll
        for (int b = 0; b < 4; ++b) acc[a][b] = (f32x4){0.f, 0.f, 0.f, 0.f};

    // ---- K-loop: no barriers, no LDS writes; compiler schedules loads ahead ----
#pragma unroll
    for (int it = 0; it < 8; ++it) {
        f16x8 af[4], bf[4];
#pragma unroll
        for (int mi = 0; mi < 4; ++mi)
            af[mi] = *(const f16x8*)(wb[mi] + it * 32);
#pragma unroll
        for (int nt = 0; nt < 4; ++nt)
            bf[nt] = *(const f16x8*)&Xs[(16 * nt + ln) * LSX + it * 32 + quad * 8];
#pragma unroll
        for (int mi = 0; mi < 4; ++mi)
#pragma unroll
            for (int nt = 0; nt < 4; ++nt)
                acc[mi][nt] = __builtin_amdgcn_mfma_f32_16x16x32_f16(af[mi], bf[nt], acc[mi][nt], 0, 0, 0);
    }
    __syncthreads();                                   // Xs reads done; arena reused below

    // prefetch W2 frags (z col 16w+ln, h col 64+16w+ln) -- fly during epilogue
    f16x8 w2f[2][4];
#pragma unroll
    for (int kc = 0; kc < 4; ++kc) {
        w2f[0][kc] = *(const f16x8*)(W2T + (size_t)(16 * wave + ln) * 128 + kc * 32 + quad * 8);
        w2f[1][kc] = *(const f16x8*)(W2T + (size_t)(64 + 16 * wave + ln) * 128 + kc * 32 + quad * 8);
    }

    // P1 epilogue: gates -> h1s. D: col(ln)=X row, row(4quad+i)=W col.
    f16* h1s = (f16*)(arena + H1S);
#pragma unroll
    for (int mi = 0; mi < 2; ++mi) {
        const int jg0 = 32 * wave + 16 * mi + (quad << 2);
        const float4 zb = *(const float4*)(bz1 + jg0);
        const float4 hb = *(const float4*)(bh1 + jg0);
#pragma unroll
        for (int nt = 0; nt < 4; ++nt) {
            const int row = 16 * nt + ln;
            f16x4 pk;
#pragma unroll
            for (int i = 0; i < 4; ++i)
                pk[i] = (f16)gate(acc[mi][nt][i] + (&zb.x)[i],
                                  acc[mi + 2][nt][i] + (&hb.x)[i]);
            *(f16x4*)&h1s[row * LSH1 + jg0] = pk;
        }
    }
    __syncthreads();

    // ---- P2: h2 = gates(h1 @ W2); wave w: z-cols 16w.., h-cols 64+16w.. ----
    f32x4 acc2[2][4];
#pragma unroll
    for (int a = 0; a < 2; ++a)
#pragma unroll
        for (int b = 0; b < 4; ++b) acc2[a][b] = (f32x4){0.f, 0.f, 0.f, 0.f};
#pragma unroll
    for (int kc = 0; kc < 4; ++kc) {
        f16x8 bf[4];
#pragma unroll
        for (int nt = 0; nt < 4; ++nt)
            bf[nt] = *(const f16x8*)&h1s[(16 * nt + ln) * LSH1 + kc * 32 + quad * 8];
#pragma unroll
        for (int m = 0; m < 2; ++m)
#pragma unroll
            for (int nt = 0; nt < 4; ++nt)
                acc2[m][nt] = __builtin_amdgcn_mfma_f32_16x16x32_f16(w2f[m][kc], bf[nt], acc2[m][nt], 0, 0, 0);
    }
    // h2s region [17408,26624) is disjoint from h1s [0,17408): no barrier needed here

    f16* h2s = (f16*)(arena + H2S);
    {
        const int jg0 = 16 * wave + (quad << 2);
        const float4 zb = *(const float4*)(bz2 + jg0);
        const float4 hb = *(const float4*)(bh2 + jg0);
#pragma unroll
        for (int nt = 0; nt < 4; ++nt) {
            const int row = 16 * nt + ln;
            f16x4 pk;
#pragma unroll
            for (int i = 0; i < 4; ++i)
                pk[i] = (f16)gate(acc2[0][nt][i] + (&zb.x)[i],
                                  acc2[1][nt][i] + (&hb.x)[i]);
            *(f16x4*)&h2s[row * LSH2 + jg0] = pk;
        }
    }
    __syncthreads();                                   // cross-wave h2s visibility for P3

    // ---- P3: out = relu(h2 @ wl1 + bl1) @ wl2 + bl2 ----
    const float blv = bl1[ln], wlv = wl2[ln], bl2v = bl2[0];
    f16x8 bfr[2];
#pragma unroll
    for (int kc = 0; kc < 2; ++kc)
#pragma unroll
        for (int j = 0; j < 8; ++j)
            bfr[kc][j] = (f16)wl1[(32 * kc + 8 * quad + j) * 16 + ln];

    f32x4 acc3 = (f32x4){0.f, 0.f, 0.f, 0.f};
#pragma unroll
    for (int kc = 0; kc < 2; ++kc) {
        f16x8 af = *(const f16x8*)&h2s[(16 * wave + ln) * LSH2 + kc * 32 + quad * 8];
        acc3 = __builtin_amdgcn_mfma_f32_16x16x32_f16(af, bfr[kc], acc3, 0, 0, 0);
    }
#pragma unroll
    for (int i = 0; i < 4; ++i) {
        float v = fmaxf(acc3[i] + blv, 0.0f) * wlv;
        v += __shfl_xor(v, 1);
        v += __shfl_xor(v, 2);
        v += __shfl_xor(v, 4);
        v += __shfl_xor(v, 8);
        if (ln == 0) {
            const int row = r0 + 16 * wave + (quad << 2) + i;
            if (row < N_ROWS) out[row] = v + bl2v;
        }
    }
}

// ---------- launch ----------
extern "C" void kernel_launch(void* const* d_in, const int* in_sizes, int n_in,
                              void* d_out, int out_size, void* d_ws, size_t ws_size,
                              hipStream_t stream) {
    const float* x   = (const float*)d_in[0];
    const float* wz1 = (const float*)d_in[3];
    const float* bz1 = (const float*)d_in[4];
    const float* wh1 = (const float*)d_in[7];
    const float* bh1 = (const float*)d_in[8];
    const float* wz2 = (const float*)d_in[9];
    const float* bz2 = (const float*)d_in[10];
    const float* wh2 = (const float*)d_in[13];
    const float* bh2 = (const float*)d_in[14];
    const float* wl1 = (const float*)d_in[15];
    const float* bl1 = (const float*)d_in[16];
    const float* wl2 = (const float*)d_in[17];
    const float* bl2 = (const float*)d_in[18];

    char* ws = (char*)d_ws;
    f16* W1T = (f16*)(ws + W1T_OFF);
    f16* W2T = (f16*)(ws + W2T_OFF);
    float* out = (float*)d_out;

    prep_w<<<320, 256, 0, stream>>>(wz1, wh1, wz2, wh2, W1T, W2T);
    fused<<<RT, 256, 0, stream>>>(x, W1T, W2T, bz1, bh1, bz2, bh2,
                                  wl1, bl1, wl2, bl2, out);
}

// Round 5
// 229.336 us; speedup vs baseline: 1.0303x; 1.0303x over previous
//
#include <hip/hip_runtime.h>

// ---------- types ----------
typedef _Float16 f16;
typedef _Float16 f16x4 __attribute__((ext_vector_type(4)));
typedef _Float16 f16x8 __attribute__((ext_vector_type(8)));
typedef float    f32x4 __attribute__((ext_vector_type(4)));

#define N_ROWS 100000
#define RT 1563           // 1563 * 64 = 100032 padded rows
#define LSX 264           // X tile f16 row stride: 256 data + 8 pad
#define LSH1 136
#define LSH2 72

// ws: fragment-linear weights.
// W1F[((M*8+it)*64 + lane)*8 + j] = (wz1|wh1 combined)[col = M*16+(lane&15)][k = it*32+(lane>>4)*8+j]
//   M 0..15 (cols: 0..127 = z, 128..255 = h), it 0..7 (K chunks of 32)
// W2F[((t*4+kc)*64 + lane)*8 + j] = (wz2|wh2 combined)[col(t)][k = kc*32+(lane>>4)*8+j]
//   t 0..3: z cols 16t+ln ; t 4..7: h cols 64+16(t-4)+ln
#define W1F_OFF 0
#define W1F_BYTES (256 * 256 * 2)
#define W2F_OFF W1F_BYTES

// arena (bytes): full X tile staged ONCE (64*264*2 = 33792); h1s/h2s overlay after K-loop
#define ARENA 33792
#define H1S 0             // 64*136*2 = 17408
#define H2S 17408         // 64*72*2  =  9216  -> 26624 <= ARENA

// ---------- prep: fragment-linear combined f16 weights ----------
__global__ void prep_w(const float* __restrict__ wz1, const float* __restrict__ wh1,
                       const float* __restrict__ wz2, const float* __restrict__ wh2,
                       f16* __restrict__ W1F, f16* __restrict__ W2F) {
    const int b = blockIdx.x, tid = threadIdx.x;
    if (b < 32) {                                  // W1F: 8192 threads, 8 f16 each
        int idx = b * 256 + tid;                   // (M*8+it)*64 + lane
        int l = idx & 63, itm = idx >> 6;
        int it = itm & 7, M = itm >> 3;
        int ln = l & 15, q = l >> 4;
        int col = M * 16 + ln;
        int k0 = it * 32 + q * 8;
        const float* w = (col < 128) ? wz1 : wh1;
        int cc = col & 127;
        f16x8 v;
#pragma unroll
        for (int j = 0; j < 8; ++j) {
            int k = k0 + j;
            v[j] = (f16)(w[k * 128 + cc] + w[384 * 128 + k * 128 + cc]);
        }
        *(f16x8*)&W1F[idx * 8] = v;
    } else {                                       // W2F: 2048 threads, 8 f16 each
        int idx = (b - 32) * 256 + tid;            // (t*4+kc)*64 + lane
        if (idx >= 2048) return;
        int l = idx & 63, tkc = idx >> 6;
        int kc = tkc & 3, t = tkc >> 2;
        int ln = l & 15, q = l >> 4;
        int col = (t < 4) ? (16 * t + ln) : (64 + 16 * (t - 4) + ln);
        int k0 = kc * 32 + q * 8;
        const float* w = (col < 64) ? wz2 : wh2;
        int cc = col & 63;
        f16x8 v;
#pragma unroll
        for (int j = 0; j < 8; ++j) {
            int k = k0 + j;
            v[j] = (f16)(w[k * 64 + cc] + w[192 * 64 + k * 64 + cc]);
        }
        *(f16x8*)&W2F[idx * 8] = v;
    }
}

// gate: relu( tanh(hp) * (1 - sigmoid(zp)) ) with a single v_rcp.
__device__ __forceinline__ float gate(float zp, float hp) {
    float e2h = __expf(2.0f * fminf(hp, 15.0f));
    float ez  = __expf(zp);
    float r   = __builtin_amdgcn_rcpf((e2h + 1.0f) * (1.0f + ez));
    return fmaxf((e2h - 1.0f) * r, 0.0f);
}

// ---------- fused: 64 rows/block; X staged to LDS once, barrier-free K-loop,
// ---------- W fragments as coalesced 1KB/wave bursts from L2 ----------
__global__ __launch_bounds__(256, 4) void fused(
    const float* __restrict__ x,
    const f16* __restrict__ W1F, const f16* __restrict__ W2F,
    const float* __restrict__ bz1, const float* __restrict__ bh1,
    const float* __restrict__ bz2, const float* __restrict__ bh2,
    const float* __restrict__ wl1, const float* __restrict__ bl1,
    const float* __restrict__ wl2, const float* __restrict__ bl2,
    float* __restrict__ out)
{
    __shared__ __align__(16) char arena[ARENA];
    const int tid = threadIdx.x, lane = tid & 63, wave = tid >> 6;
    const int ln = lane & 15, quad = lane >> 4;
    const int r0 = blockIdx.x * 64;

    // staging thread mapping (X only): thread -> (row, 8-float col group)
    const int xr = tid >> 2, xcg = tid & 3;
    int gxr = r0 + xr; if (gxr >= N_ROWS) gxr = N_ROWS - 1;
    const float* xp = x + (size_t)gxr * 256 + (xcg << 3);

    f16* Xs = (f16*)arena;

    // ---- stage the full 64x256 tile in two 4-chunk halves (<=32 live f32, no spill) ----
#pragma unroll
    for (int half = 0; half < 2; ++half) {
        float4 xa[4], xb[4];
#pragma unroll
        for (int kc = 0; kc < 4; ++kc) {
            xa[kc] = *(const float4*)(xp + (half * 4 + kc) * 32);
            xb[kc] = *(const float4*)(xp + (half * 4 + kc) * 32 + 4);
        }
#pragma unroll
        for (int kc = 0; kc < 4; ++kc) {
            *(f16x8*)&Xs[xr * LSX + (half * 4 + kc) * 32 + (xcg << 3)] =
                (f16x8){(f16)xa[kc].x,(f16)xa[kc].y,(f16)xa[kc].z,(f16)xa[kc].w,
                        (f16)xb[kc].x,(f16)xb[kc].y,(f16)xb[kc].z,(f16)xb[kc].w};
        }
    }

    // P1 wave tiles: z m-tiles {2w,2w+1}, h {2w+8,2w+9}; n-tiles 0..3 (16 rows each)
    const int Mz = 2 * wave;
    const f16* wb[4];
#pragma unroll
    for (int mi = 0; mi < 4; ++mi) {
        const int M = (mi < 2) ? (Mz + mi) : (8 + Mz + mi - 2);
        wb[mi] = W1F + ((size_t)(M * 8) * 64 + lane) * 8;   // + it*512 per iter
    }

    __syncthreads();

    f32x4 acc[4][4];                                   // [mi][nt]
#pragma unroll
    for (int a = 0; a < 4; ++a)
#pragma unroll
        for (int b = 0; b < 4; ++b) acc[a][b] = (f32x4){0.f, 0.f, 0.f, 0.f};

    // ---- K-loop: no barriers, no LDS writes; af loads are 1KB coalesced bursts ----
#pragma unroll
    for (int it = 0; it < 8; ++it) {
        f16x8 af[4], bf[4];
#pragma unroll
        for (int mi = 0; mi < 4; ++mi)
            af[mi] = *(const f16x8*)(wb[mi] + it * 512);
#pragma unroll
        for (int nt = 0; nt < 4; ++nt)
            bf[nt] = *(const f16x8*)&Xs[(16 * nt + ln) * LSX + it * 32 + quad * 8];
#pragma unroll
        for (int mi = 0; mi < 4; ++mi)
#pragma unroll
            for (int nt = 0; nt < 4; ++nt)
                acc[mi][nt] = __builtin_amdgcn_mfma_f32_16x16x32_f16(af[mi], bf[nt], acc[mi][nt], 0, 0, 0);
    }
    __syncthreads();                                   // Xs reads done; arena reused below

    // prefetch W2 frags (coalesced) -- fly during epilogue
    f16x8 w2f[2][4];
#pragma unroll
    for (int kc = 0; kc < 4; ++kc) {
        w2f[0][kc] = *(const f16x8*)(W2F + ((size_t)((wave    ) * 4 + kc) * 64 + lane) * 8);
        w2f[1][kc] = *(const f16x8*)(W2F + ((size_t)((wave + 4) * 4 + kc) * 64 + lane) * 8);
    }

    // P1 epilogue: gates -> h1s. D: col(ln)=X row, row(4quad+i)=W col.
    f16* h1s = (f16*)(arena + H1S);
#pragma unroll
    for (int mi = 0; mi < 2; ++mi) {
        const int jg0 = 32 * wave + 16 * mi + (quad << 2);
        const float4 zb = *(const float4*)(bz1 + jg0);
        const float4 hb = *(const float4*)(bh1 + jg0);
#pragma unroll
        for (int nt = 0; nt < 4; ++nt) {
            const int row = 16 * nt + ln;
            f16x4 pk;
#pragma unroll
            for (int i = 0; i < 4; ++i)
                pk[i] = (f16)gate(acc[mi][nt][i] + (&zb.x)[i],
                                  acc[mi + 2][nt][i] + (&hb.x)[i]);
            *(f16x4*)&h1s[row * LSH1 + jg0] = pk;
        }
    }
    __syncthreads();

    // ---- P2: h2 = gates(h1 @ W2); wave w: z-cols 16w.., h-cols 64+16w.. ----
    f32x4 acc2[2][4];
#pragma unroll
    for (int a = 0; a < 2; ++a)
#pragma unroll
        for (int b = 0; b < 4; ++b) acc2[a][b] = (f32x4){0.f, 0.f, 0.f, 0.f};
#pragma unroll
    for (int kc = 0; kc < 4; ++kc) {
        f16x8 bf[4];
#pragma unroll
        for (int nt = 0; nt < 4; ++nt)
            bf[nt] = *(const f16x8*)&h1s[(16 * nt + ln) * LSH1 + kc * 32 + quad * 8];
#pragma unroll
        for (int m = 0; m < 2; ++m)
#pragma unroll
            for (int nt = 0; nt < 4; ++nt)
                acc2[m][nt] = __builtin_amdgcn_mfma_f32_16x16x32_f16(w2f[m][kc], bf[nt], acc2[m][nt], 0, 0, 0);
    }
    // h2s region [17408,26624) disjoint from h1s [0,17408): no barrier needed here

    f16* h2s = (f16*)(arena + H2S);
    {
        const int jg0 = 16 * wave + (quad << 2);
        const float4 zb = *(const float4*)(bz2 + jg0);
        const float4 hb = *(const float4*)(bh2 + jg0);
#pragma unroll
        for (int nt = 0; nt < 4; ++nt) {
            const int row = 16 * nt + ln;
            f16x4 pk;
#pragma unroll
            for (int i = 0; i < 4; ++i)
                pk[i] = (f16)gate(acc2[0][nt][i] + (&zb.x)[i],
                                  acc2[1][nt][i] + (&hb.x)[i]);
            *(f16x4*)&h2s[row * LSH2 + jg0] = pk;
        }
    }
    __syncthreads();                                   // cross-wave h2s visibility for P3

    // ---- P3: out = relu(h2 @ wl1 + bl1) @ wl2 + bl2 ----
    const float blv = bl1[ln], wlv = wl2[ln], bl2v = bl2[0];
    f16x8 bfr[2];
#pragma unroll
    for (int kc = 0; kc < 2; ++kc)
#pragma unroll
        for (int j = 0; j < 8; ++j)
            bfr[kc][j] = (f16)wl1[(32 * kc + 8 * quad + j) * 16 + ln];

    f32x4 acc3 = (f32x4){0.f, 0.f, 0.f, 0.f};
#pragma unroll
    for (int kc = 0; kc < 2; ++kc) {
        f16x8 af = *(const f16x8*)&h2s[(16 * wave + ln) * LSH2 + kc * 32 + quad * 8];
        acc3 = __builtin_amdgcn_mfma_f32_16x16x32_f16(af, bfr[kc], acc3, 0, 0, 0);
    }
#pragma unroll
    for (int i = 0; i < 4; ++i) {
        float v = fmaxf(acc3[i] + blv, 0.0f) * wlv;
        v += __shfl_xor(v, 1);
        v += __shfl_xor(v, 2);
        v += __shfl_xor(v, 4);
        v += __shfl_xor(v, 8);
        if (ln == 0) {
            const int row = r0 + 16 * wave + (quad << 2) + i;
            if (row < N_ROWS) out[row] = v + bl2v;
        }
    }
}

// ---------- launch ----------
extern "C" void kernel_launch(void* const* d_in, const int* in_sizes, int n_in,
                              void* d_out, int out_size, void* d_ws, size_t ws_size,
                              hipStream_t stream) {
    const float* x   = (const float*)d_in[0];
    const float* wz1 = (const float*)d_in[3];
    const float* bz1 = (const float*)d_in[4];
    const float* wh1 = (const float*)d_in[7];
    const float* bh1 = (const float*)d_in[8];
    const float* wz2 = (const float*)d_in[9];
    const float* bz2 = (const float*)d_in[10];
    const float* wh2 = (const float*)d_in[13];
    const float* bh2 = (const float*)d_in[14];
    const float* wl1 = (const float*)d_in[15];
    const float* bl1 = (const float*)d_in[16];
    const float* wl2 = (const float*)d_in[17];
    const float* bl2 = (const float*)d_in[18];

    char* ws = (char*)d_ws;
    f16* W1F = (f16*)(ws + W1F_OFF);
    f16* W2F = (f16*)(ws + W2F_OFF);
    float* out = (float*)d_out;

    prep_w<<<40, 256, 0, stream>>>(wz1, wh1, wz2, wh2, W1F, W2F);
    fused<<<RT, 256, 0, stream>>>(x, W1F, W2F, bz1, bh1, bz2, bh2,
                                  wl1, bl1, wl2, bl2, out);
}

// Round 7
// 221.366 us; speedup vs baseline: 1.0674x; 1.0360x over previous
//
#include <hip/hip_runtime.h>

// ---------- types ----------
typedef _Float16 f16;
typedef _Float16 f16x4 __attribute__((ext_vector_type(4)));
typedef _Float16 f16x8 __attribute__((ext_vector_type(8)));
typedef float    f32x4 __attribute__((ext_vector_type(4)));

#define N_ROWS 100000
#define RT 782            // 782 * 128 = 100096 padded rows
#define TPB 512
#define LSX 264           // X tile f16 row stride: 256 data + 8 pad
#define LSH1 136
#define LSH2 72

// ws: fragment-linear weights.
// W1F[((M*8+it)*64 + lane)*8 + j] = Wcomb1[col = M*16+(lane&15)][k = it*32+(lane>>4)*8+j]
//   M 0..15 (cols: 0..127 = z, 128..255 = h), it 0..7
// W2F[((t*4+kc)*64 + lane)*8 + j] = Wcomb2[col(t)][k = kc*32+(lane>>4)*8+j]
//   t 0..3: z cols 16t+ln ; t 4..7: h cols 64+16(t-4)+ln
#define W1F_OFF 0
#define W1F_BYTES (256 * 256 * 2)
#define W2F_OFF W1F_BYTES

// arena: X tile 128*264*2 = 67584; h1s/h2s overlay after K-loop
#define ARENA 67584
#define H1S 0             // 128*136*2 = 34816
#define H2S 34816         // 128*72*2  = 18432 -> 53248 <= ARENA

// ---------- prep: fragment-linear combined f16 weights ----------
__global__ void prep_w(const float* __restrict__ wz1, const float* __restrict__ wh1,
                       const float* __restrict__ wz2, const float* __restrict__ wh2,
                       f16* __restrict__ W1F, f16* __restrict__ W2F) {
    const int b = blockIdx.x, tid = threadIdx.x;
    if (b < 32) {                                  // W1F: 8192 threads, 8 f16 each
        int idx = b * 256 + tid;                   // (M*8+it)*64 + lane
        int l = idx & 63, itm = idx >> 6;
        int it = itm & 7, M = itm >> 3;
        int ln = l & 15, q = l >> 4;
        int col = M * 16 + ln;
        int k0 = it * 32 + q * 8;
        const float* w = (col < 128) ? wz1 : wh1;
        int cc = col & 127;
        f16x8 v;
#pragma unroll
        for (int j = 0; j < 8; ++j) {
            int k = k0 + j;
            v[j] = (f16)(w[k * 128 + cc] + w[384 * 128 + k * 128 + cc]);
        }
        *(f16x8*)&W1F[idx * 8] = v;
    } else {                                       // W2F: 2048 threads, 8 f16 each
        int idx = (b - 32) * 256 + tid;            // (t*4+kc)*64 + lane
        if (idx >= 2048) return;
        int l = idx & 63, tkc = idx >> 6;
        int kc = tkc & 3, t = tkc >> 2;
        int ln = l & 15, q = l >> 4;
        int col = (t < 4) ? (16 * t + ln) : (64 + 16 * (t - 4) + ln);
        int k0 = kc * 32 + q * 8;
        const float* w = (col < 64) ? wz2 : wh2;
        int cc = col & 63;
        f16x8 v;
#pragma unroll
        for (int j = 0; j < 8; ++j) {
            int k = k0 + j;
            v[j] = (f16)(w[k * 64 + cc] + w[192 * 64 + k * 64 + cc]);
        }
        *(f16x8*)&W2F[idx * 8] = v;
    }
}

// gate: relu( tanh(hp) * (1 - sigmoid(zp)) ) with a single v_rcp.
__device__ __forceinline__ float gate(float zp, float hp) {
    float e2h = __expf(2.0f * fminf(hp, 15.0f));
    float ez  = __expf(zp);
    float r   = __builtin_amdgcn_rcpf((e2h + 1.0f) * (1.0f + ez));
    return fmaxf((e2h - 1.0f) * r, 0.0f);
}

// ---------- fused: 128 rows/block, 8 waves; wave w owns W-col pair {w, w+8} ----------
__global__ __launch_bounds__(TPB, 4) void fused(
    const float* __restrict__ x,
    const f16* __restrict__ W1F, const f16* __restrict__ W2F,
    const float* __restrict__ bz1, const float* __restrict__ bh1,
    const float* __restrict__ bz2, const float* __restrict__ bh2,
    const float* __restrict__ wl1, const float* __restrict__ bl1,
    const float* __restrict__ wl2, const float* __restrict__ bl2,
    float* __restrict__ out)
{
    __shared__ __align__(16) char arena[ARENA];
    const int tid = threadIdx.x, lane = tid & 63, wave = tid >> 6;
    const int ln = lane & 15, quad = lane >> 4;
    const int r0 = blockIdx.x * 128;

    // staging: 4 threads per row, 64 f32 per thread, convert+write immediately (no spill)
    const int xr = tid >> 2, xcg = tid & 3;
    int gxr = r0 + xr; if (gxr >= N_ROWS) gxr = N_ROWS - 1;
    const float* xp = x + (size_t)gxr * 256 + (xcg << 3);

    f16* Xs = (f16*)arena;
#pragma unroll 2
    for (int kc = 0; kc < 8; ++kc) {
        f32x4 a = __builtin_nontemporal_load((const f32x4*)(xp + kc * 32));
        f32x4 b = __builtin_nontemporal_load((const f32x4*)(xp + kc * 32 + 4));
        *(f16x8*)&Xs[xr * LSX + kc * 32 + (xcg << 3)] =
            (f16x8){(f16)a[0],(f16)a[1],(f16)a[2],(f16)a[3],
                    (f16)b[0],(f16)b[1],(f16)b[2],(f16)b[3]};
    }

    // P1: wave w computes z m-tile w (cols 16w..16w+15) and h m-tile w+8, all 8 n-tiles
    const f16* wbz = W1F + ((size_t)(wave * 8) * 64 + lane) * 8;        // + it*512
    const f16* wbh = W1F + ((size_t)((wave + 8) * 8) * 64 + lane) * 8;  // + it*512

    __syncthreads();

    f32x4 acc[2][8];                                   // [z|h][nt], 64 AGPR
#pragma unroll
    for (int a = 0; a < 2; ++a)
#pragma unroll
        for (int b = 0; b < 8; ++b) acc[a][b] = (f32x4){0.f, 0.f, 0.f, 0.f};

    // ---- K-loop: barrier-free; af = 1KB coalesced burst per wave, bf from LDS ----
#pragma unroll
    for (int it = 0; it < 8; ++it) {
        f16x8 afz = *(const f16x8*)(wbz + it * 512);
        f16x8 afh = *(const f16x8*)(wbh + it * 512);
        f16x8 bf[8];
#pragma unroll
        for (int nt = 0; nt < 8; ++nt)
            bf[nt] = *(const f16x8*)&Xs[(16 * nt + ln) * LSX + it * 32 + quad * 8];
#pragma unroll
        for (int nt = 0; nt < 8; ++nt)
            acc[0][nt] = __builtin_amdgcn_mfma_f32_16x16x32_f16(afz, bf[nt], acc[0][nt], 0, 0, 0);
#pragma unroll
        for (int nt = 0; nt < 8; ++nt)
            acc[1][nt] = __builtin_amdgcn_mfma_f32_16x16x32_f16(afh, bf[nt], acc[1][nt], 0, 0, 0);
    }
    __syncthreads();                                   // Xs reads done; arena reused below

    // prefetch W2 frags (coalesced) -- wave w: col-tile c=w&3, row-half rh=w>>2
    const int c = wave & 3, rh = wave >> 2;
    f16x8 w2f[2][4];
#pragma unroll
    for (int kc = 0; kc < 4; ++kc) {
        w2f[0][kc] = *(const f16x8*)(W2F + ((size_t)((c    ) * 4 + kc) * 64 + lane) * 8);
        w2f[1][kc] = *(const f16x8*)(W2F + ((size_t)((c + 4) * 4 + kc) * 64 + lane) * 8);
    }

    // P1 epilogue: gates -> h1s. D: col(ln)=X row, row(4quad+i)=W col (within tile).
    f16* h1s = (f16*)(arena + H1S);
    {
        const int jg0 = 16 * wave + (quad << 2);
        const float4 zb = *(const float4*)(bz1 + jg0);
        const float4 hb = *(const float4*)(bh1 + jg0);
#pragma unroll
        for (int nt = 0; nt < 8; ++nt) {
            const int row = 16 * nt + ln;
            f16x4 pk;
#pragma unroll
            for (int i = 0; i < 4; ++i)
                pk[i] = (f16)gate(acc[0][nt][i] + (&zb.x)[i],
                                  acc[1][nt][i] + (&hb.x)[i]);
            *(f16x4*)&h1s[row * LSH1 + jg0] = pk;
        }
    }
    __syncthreads();

    // ---- P2: h2 = gates(h1 @ W2); wave w: z-cols 16c.., h-cols 64+16c.., rows 64*rh.. ----
    f32x4 acc2[2][4];
#pragma unroll
    for (int a = 0; a < 2; ++a)
#pragma unroll
        for (int b = 0; b < 4; ++b) acc2[a][b] = (f32x4){0.f, 0.f, 0.f, 0.f};
#pragma unroll
    for (int kc = 0; kc < 4; ++kc) {
        f16x8 bf[4];
#pragma unroll
        for (int nt = 0; nt < 4; ++nt)
            bf[nt] = *(const f16x8*)&h1s[(16 * (4 * rh + nt) + ln) * LSH1 + kc * 32 + quad * 8];
#pragma unroll
        for (int m = 0; m < 2; ++m)
#pragma unroll
            for (int nt = 0; nt < 4; ++nt)
                acc2[m][nt] = __builtin_amdgcn_mfma_f32_16x16x32_f16(w2f[m][kc], bf[nt], acc2[m][nt], 0, 0, 0);
    }
    // h2s region [34816,53248) disjoint from h1s [0,34816): no barrier needed here

    f16* h2s = (f16*)(arena + H2S);
    {
        const int jg0 = 16 * c + (quad << 2);
        const float4 zb = *(const float4*)(bz2 + jg0);
        const float4 hb = *(const float4*)(bh2 + jg0);
#pragma unroll
        for (int nt = 0; nt < 4; ++nt) {
            const int row = 16 * (4 * rh + nt) + ln;
            f16x4 pk;
#pragma unroll
            for (int i = 0; i < 4; ++i)
                pk[i] = (f16)gate(acc2[0][nt][i] + (&zb.x)[i],
                                  acc2[1][nt][i] + (&hb.x)[i]);
            *(f16x4*)&h2s[row * LSH2 + jg0] = pk;
        }
    }
    __syncthreads();                                   // cross-wave h2s visibility for P3

    // ---- P3: out = relu(h2 @ wl1 + bl1) @ wl2 + bl2 ; wave w: rows 16w+ln ----
    const float blv = bl1[ln], wlv = wl2[ln], bl2v = bl2[0];
    f16x8 bfr[2];
#pragma unroll
    for (int kc = 0; kc < 2; ++kc)
#pragma unroll
        for (int j = 0; j < 8; ++j)
            bfr[kc][j] = (f16)wl1[(32 * kc + 8 * quad + j) * 16 + ln];

    f32x4 acc3 = (f32x4){0.f, 0.f, 0.f, 0.f};
#pragma unroll
    for (int kc = 0; kc < 2; ++kc) {
        f16x8 af = *(const f16x8*)&h2s[(16 * wave + ln) * LSH2 + kc * 32 + quad * 8];
        acc3 = __builtin_amdgcn_mfma_f32_16x16x32_f16(af, bfr[kc], acc3, 0, 0, 0);
    }
#pragma unroll
    for (int i = 0; i < 4; ++i) {
        float v = fmaxf(acc3[i] + blv, 0.0f) * wlv;
        v += __shfl_xor(v, 1);
        v += __shfl_xor(v, 2);
        v += __shfl_xor(v, 4);
        v += __shfl_xor(v, 8);
        if (ln == 0) {
            const int row = r0 + 16 * wave + (quad << 2) + i;
            if (row < N_ROWS) out[row] = v + bl2v;
        }
    }
}

// ---------- launch ----------
extern "C" void kernel_launch(void* const* d_in, const int* in_sizes, int n_in,
                              void* d_out, int out_size, void* d_ws, size_t ws_size,
                              hipStream_t stream) {
    const float* x   = (const float*)d_in[0];
    const float* wz1 = (const float*)d_in[3];
    const float* bz1 = (const float*)d_in[4];
    const float* wh1 = (const float*)d_in[7];
    const float* bh1 = (const float*)d_in[8];
    const float* wz2 = (const float*)d_in[9];
    const float* bz2 = (const float*)d_in[10];
    const float* wh2 = (const float*)d_in[13];
    const float* bh2 = (const float*)d_in[14];
    const float* wl1 = (const float*)d_in[15];
    const float* bl1 = (const float*)d_in[16];
    const float* wl2 = (const float*)d_in[17];
    const float* bl2 = (const float*)d_in[18];

    char* ws = (char*)d_ws;
    f16* W1F = (f16*)(ws + W1F_OFF);
    f16* W2F = (f16*)(ws + W2F_OFF);
    float* out = (float*)d_out;

    prep_w<<<40, 256, 0, stream>>>(wz1, wh1, wz2, wh2, W1F, W2F);
    fused<<<RT, TPB, 0, stream>>>(x, W1F, W2F, bz1, bh1, bz2, bh2,
                                  wl1, bl1, wl2, bl2, out);
}

// Round 9
// 219.174 us; speedup vs baseline: 1.0781x; 1.0100x over previous
//
#include <hip/hip_runtime.h>

// ---------- types ----------
typedef _Float16 f16;
typedef _Float16 f16x4 __attribute__((ext_vector_type(4)));
typedef _Float16 f16x8 __attribute__((ext_vector_type(8)));
typedef float    f32x4 __attribute__((ext_vector_type(4)));

#define N_ROWS 100000
#define RT 782            // 782 * 128 = 100096 padded rows
#define TPB 512
#define LSX 264           // X tile f16 row stride: 256 data + 8 pad
#define LSH1 136
#define LSH2 72

// ws: fragment-linear weights.
// W1F[((M*8+it)*64 + lane)*8 + j] = Wcomb1[col = M*16+(lane&15)][k = it*32+(lane>>4)*8+j]
// W2F[((t*4+kc)*64 + lane)*8 + j] = Wcomb2[col(t)][k = kc*32+(lane>>4)*8+j]
#define W1F_OFF 0
#define W1F_BYTES (256 * 256 * 2)
#define W2F_OFF W1F_BYTES

// arena: X tile 128*264*2 = 67584; h1s/h2s overlay after K-loop
#define ARENA 67584
#define H1S 0             // 128*136*2 = 34816
#define H2S 34816         // 128*72*2  = 18432 -> 53248 <= ARENA

// ---------- prep: fragment-linear combined f16 weights ----------
__global__ void prep_w(const float* __restrict__ wz1, const float* __restrict__ wh1,
                       const float* __restrict__ wz2, const float* __restrict__ wh2,
                       f16* __restrict__ W1F, f16* __restrict__ W2F) {
    const int b = blockIdx.x, tid = threadIdx.x;
    if (b < 32) {                                  // W1F: 8192 threads, 8 f16 each
        int idx = b * 256 + tid;                   // (M*8+it)*64 + lane
        int l = idx & 63, itm = idx >> 6;
        int it = itm & 7, M = itm >> 3;
        int ln = l & 15, q = l >> 4;
        int col = M * 16 + ln;
        int k0 = it * 32 + q * 8;
        const float* w = (col < 128) ? wz1 : wh1;
        int cc = col & 127;
        f16x8 v;
#pragma unroll
        for (int j = 0; j < 8; ++j) {
            int k = k0 + j;
            v[j] = (f16)(w[k * 128 + cc] + w[384 * 128 + k * 128 + cc]);
        }
        *(f16x8*)&W1F[idx * 8] = v;
    } else {                                       // W2F: 2048 threads, 8 f16 each
        int idx = (b - 32) * 256 + tid;            // (t*4+kc)*64 + lane
        if (idx >= 2048) return;
        int l = idx & 63, tkc = idx >> 6;
        int kc = tkc & 3, t = tkc >> 2;
        int ln = l & 15, q = l >> 4;
        int col = (t < 4) ? (16 * t + ln) : (64 + 16 * (t - 4) + ln);
        int k0 = kc * 32 + q * 8;
        const float* w = (col < 64) ? wz2 : wh2;
        int cc = col & 63;
        f16x8 v;
#pragma unroll
        for (int j = 0; j < 8; ++j) {
            int k = k0 + j;
            v[j] = (f16)(w[k * 64 + cc] + w[192 * 64 + k * 64 + cc]);
        }
        *(f16x8*)&W2F[idx * 8] = v;
    }
}

// gate: relu( tanh(hp) * (1 - sigmoid(zp)) ) with a single v_rcp.
__device__ __forceinline__ float gate(float zp, float hp) {
    float e2h = __expf(2.0f * fminf(hp, 15.0f));
    float ez  = __expf(zp);
    float r   = __builtin_amdgcn_rcpf((e2h + 1.0f) * (1.0f + ez));
    return fmaxf((e2h - 1.0f) * r, 0.0f);
}

// ---------- fused: 128 rows/block, 8 waves; X staged in 8 pipelined 32-col slices ----------
__global__ __launch_bounds__(TPB, 4) void fused(
    const float* __restrict__ x,
    const f16* __restrict__ W1F, const f16* __restrict__ W2F,
    const float* __restrict__ bz1, const float* __restrict__ bh1,
    const float* __restrict__ bz2, const float* __restrict__ bh2,
    const float* __restrict__ wl1, const float* __restrict__ bl1,
    const float* __restrict__ wl2, const float* __restrict__ bl2,
    float* __restrict__ out)
{
    __shared__ __align__(16) char arena[ARENA];
    const int tid = threadIdx.x, lane = tid & 63, wave = tid >> 6;
    const int ln = lane & 15, quad = lane >> 4;
    const int r0 = blockIdx.x * 128;

    // slice staging map: 4 threads/row, 8 f32 each (cols s*32 + (tid&3)*8 ..)
    const int xr = tid >> 2, xcg = tid & 3;
    int gxr = r0 + xr; if (gxr >= N_ROWS) gxr = N_ROWS - 1;
    const float* xp = x + (size_t)gxr * 256 + (xcg << 3);

    f16* Xs = (f16*)arena;

    // P1: wave w computes z m-tile w (cols 16w..) and h m-tile w+8, all 8 n-tiles
    const f16* wbz = W1F + ((size_t)(wave * 8) * 64 + lane) * 8;        // + it*512
    const f16* wbh = W1F + ((size_t)((wave + 8) * 8) * 64 + lane) * 8;  // + it*512

    f32x4 acc[2][8];                                   // [z|h][nt], 64 AGPR
#pragma unroll
    for (int a = 0; a < 2; ++a)
#pragma unroll
        for (int b = 0; b < 8; ++b) acc[a][b] = (f32x4){0.f, 0.f, 0.f, 0.f};

    // prologue: slice 0 + W frags 0 in regs
    f32x4 pa = __builtin_nontemporal_load((const f32x4*)(xp));
    f32x4 pb = __builtin_nontemporal_load((const f32x4*)(xp + 4));
    f16x8 afz = *(const f16x8*)(wbz);
    f16x8 afh = *(const f16x8*)(wbh);

    // ---- pipelined stage+compute: commit s | barrier | issue s+1 | K-iter s ----
#pragma unroll
    for (int s = 0; s < 8; ++s) {
        *(f16x8*)&Xs[xr * LSX + s * 32 + (xcg << 3)] =
            (f16x8){(f16)pa[0],(f16)pa[1],(f16)pa[2],(f16)pa[3],
                    (f16)pb[0],(f16)pb[1],(f16)pb[2],(f16)pb[3]};
        __syncthreads();
        f16x8 afz_n, afh_n;
        if (s < 7) {
            pa = __builtin_nontemporal_load((const f32x4*)(xp + (s + 1) * 32));
            pb = __builtin_nontemporal_load((const f32x4*)(xp + (s + 1) * 32 + 4));
            afz_n = *(const f16x8*)(wbz + (s + 1) * 512);
            afh_n = *(const f16x8*)(wbh + (s + 1) * 512);
        }
        __builtin_amdgcn_sched_barrier(0);             // pin prefetch issue before MFMAs
#pragma unroll
        for (int nt = 0; nt < 8; ++nt) {
            f16x8 bf = *(const f16x8*)&Xs[(16 * nt + ln) * LSX + s * 32 + quad * 8];
            acc[0][nt] = __builtin_amdgcn_mfma_f32_16x16x32_f16(afz, bf, acc[0][nt], 0, 0, 0);
            acc[1][nt] = __builtin_amdgcn_mfma_f32_16x16x32_f16(afh, bf, acc[1][nt], 0, 0, 0);
        }
        afz = afz_n; afh = afh_n;
    }
    __syncthreads();                                   // Xs reads done; arena reused below

    // prefetch W2 frags (coalesced) -- wave w: col-tile c=w&3, row-half rh=w>>2
    const int c = wave & 3, rh = wave >> 2;
    f16x8 w2f[2][4];
#pragma unroll
    for (int kc = 0; kc < 4; ++kc) {
        w2f[0][kc] = *(const f16x8*)(W2F + ((size_t)((c    ) * 4 + kc) * 64 + lane) * 8);
        w2f[1][kc] = *(const f16x8*)(W2F + ((size_t)((c + 4) * 4 + kc) * 64 + lane) * 8);
    }

    // P1 epilogue: gates -> h1s. D: col(ln)=X row, row(4quad+i)=W col (within tile).
    f16* h1s = (f16*)(arena + H1S);
    {
        const int jg0 = 16 * wave + (quad << 2);
        const float4 zb = *(const float4*)(bz1 + jg0);
        const float4 hb = *(const float4*)(bh1 + jg0);
#pragma unroll
        for (int nt = 0; nt < 8; ++nt) {
            const int row = 16 * nt + ln;
            f16x4 pk;
#pragma unroll
            for (int i = 0; i < 4; ++i)
                pk[i] = (f16)gate(acc[0][nt][i] + (&zb.x)[i],
                                  acc[1][nt][i] + (&hb.x)[i]);
            *(f16x4*)&h1s[row * LSH1 + jg0] = pk;
        }
    }
    __syncthreads();

    // ---- P2: h2 = gates(h1 @ W2); wave w: z-cols 16c.., h-cols 64+16c.., rows 64*rh.. ----
    f32x4 acc2[2][4];
#pragma unroll
    for (int a = 0; a < 2; ++a)
#pragma unroll
        for (int b = 0; b < 4; ++b) acc2[a][b] = (f32x4){0.f, 0.f, 0.f, 0.f};
#pragma unroll
    for (int kc = 0; kc < 4; ++kc) {
        f16x8 bf[4];
#pragma unroll
        for (int nt = 0; nt < 4; ++nt)
            bf[nt] = *(const f16x8*)&h1s[(16 * (4 * rh + nt) + ln) * LSH1 + kc * 32 + quad * 8];
#pragma unroll
        for (int m = 0; m < 2; ++m)
#pragma unroll
            for (int nt = 0; nt < 4; ++nt)
                acc2[m][nt] = __builtin_amdgcn_mfma_f32_16x16x32_f16(w2f[m][kc], bf[nt], acc2[m][nt], 0, 0, 0);
    }
    // h2s region [34816,53248) disjoint from h1s [0,34816): no barrier needed here

    f16* h2s = (f16*)(arena + H2S);
    {
        const int jg0 = 16 * c + (quad << 2);
        const float4 zb = *(const float4*)(bz2 + jg0);
        const float4 hb = *(const float4*)(bh2 + jg0);
#pragma unroll
        for (int nt = 0; nt < 4; ++nt) {
            const int row = 16 * (4 * rh + nt) + ln;
            f16x4 pk;
#pragma unroll
            for (int i = 0; i < 4; ++i)
                pk[i] = (f16)gate(acc2[0][nt][i] + (&zb.x)[i],
                                  acc2[1][nt][i] + (&hb.x)[i]);
            *(f16x4*)&h2s[row * LSH2 + jg0] = pk;
        }
    }
    __syncthreads();                                   // cross-wave h2s visibility for P3

    // ---- P3: out = relu(h2 @ wl1 + bl1) @ wl2 + bl2 ; wave w: rows 16w+ln ----
    const float blv = bl1[ln], wlv = wl2[ln], bl2v = bl2[0];
    f16x8 bfr[2];
#pragma unroll
    for (int kc = 0; kc < 2; ++kc)
#pragma unroll
        for (int j = 0; j < 8; ++j)
            bfr[kc][j] = (f16)wl1[(32 * kc + 8 * quad + j) * 16 + ln];

    f32x4 acc3 = (f32x4){0.f, 0.f, 0.f, 0.f};
#pragma unroll
    for (int kc = 0; kc < 2; ++kc) {
        f16x8 af = *(const f16x8*)&h2s[(16 * wave + ln) * LSH2 + kc * 32 + quad * 8];
        acc3 = __builtin_amdgcn_mfma_f32_16x16x32_f16(af, bfr[kc], acc3, 0, 0, 0);
    }
#pragma unroll
    for (int i = 0; i < 4; ++i) {
        float v = fmaxf(acc3[i] + blv, 0.0f) * wlv;
        v += __shfl_xor(v, 1);
        v += __shfl_xor(v, 2);
        v += __shfl_xor(v, 4);
        v += __shfl_xor(v, 8);
        if (ln == 0) {
            const int row = r0 + 16 * wave + (quad << 2) + i;
            if (row < N_ROWS) out[row] = v + bl2v;
        }
    }
}

// ---------- launch ----------
extern "C" void kernel_launch(void* const* d_in, const int* in_sizes, int n_in,
                              void* d_out, int out_size, void* d_ws, size_t ws_size,
                              hipStream_t stream) {
    const float* x   = (const float*)d_in[0];
    const float* wz1 = (const float*)d_in[3];
    const float* bz1 = (const float*)d_in[4];
    const float* wh1 = (const float*)d_in[7];
    const float* bh1 = (const float*)d_in[8];
    const float* wz2 = (const float*)d_in[9];
    const float* bz2 = (const float*)d_in[10];
    const float* wh2 = (const float*)d_in[13];
    const float* bh2 = (const float*)d_in[14];
    const float* wl1 = (const float*)d_in[15];
    const float* bl1 = (const float*)d_in[16];
    const float* wl2 = (const float*)d_in[17];
    const float* bl2 = (const float*)d_in[18];

    char* ws = (char*)d_ws;
    f16* W1F = (f16*)(ws + W1F_OFF);
    f16* W2F = (f16*)(ws + W2F_OFF);
    float* out = (float*)d_out;

    prep_w<<<40, 256, 0, stream>>>(wz1, wh1, wz2, wh2, W1F, W2F);
    fused<<<RT, TPB, 0, stream>>>(x, W1F, W2F, bz1, bh1, bz2, bh2,
                                  wl1, bl1, wl2, bl2, out);
}